// Round 12
// baseline (482.058 us; speedup 1.0000x reference)
//
#include <hip/hip_runtime.h>
#include <hip/hip_bf16.h>
#include <stdint.h>

// GAT layer, MI355X. N=8192, F_in=256, F_out=128. All-f32 I/O (validated R9+).
// R12: (a) s1/s2 via wa=W@a trick -> exact fp32 matvec, k_xw becomes plain bf16 GEMM
//      (hi-only, 77 KB LDS, 2 blocks/CU); (b) k_attn re-tiled 64 rows x 1024 cols
//      (j-split 8): half the barriers/HS-staging, deeper adj prefetch.

#define N_NODES 8192
#define F_INF   256
#define F_OUT   128
#define LRELU   0.01f

typedef __bf16 bf16x8 __attribute__((ext_vector_type(8)));
typedef float  f32x4  __attribute__((ext_vector_type(4)));
using bf16 = __hip_bfloat16;

__device__ __forceinline__ float b2f(bf16 v) { return __bfloat162float(v); }
__device__ __forceinline__ bf16  f2b(float v) { return __float2bfloat16(v); }

// ---------------- kernel 0: wa1 = W@a1, wa2 = W@a2 (exact fp32) ----------------
__global__ __launch_bounds__(256) void k_wa(const float* __restrict__ W,
                                            const float* __restrict__ a,
                                            float* __restrict__ wa) {
    const int k = threadIdx.x;  // 0..255
    const float* wr = W + (size_t)k * F_OUT;
    float v1 = 0.f, v2 = 0.f;
    for (int f = 0; f < F_OUT; ++f) {
        float w = wr[f];
        v1 += w * a[f];
        v2 += w * a[F_OUT + f];
    }
    wa[k] = v1;
    wa[F_INF + k] = v2;
}

// ---------------- kernel 1: hT[f][i] = bf16(x@W), plain bf16 GEMM ----------------
// block: 64 rows, 256 threads = 4 waves; wave = 16-row tile, all 8 col-tiles.
__global__ __launch_bounds__(256) void k_xw(const float* __restrict__ x,
                                            const float* __restrict__ W,
                                            bf16* __restrict__ hT) {
    __shared__ __align__(16) bf16 WT[F_OUT][F_INF + 8];  // 67.6 KB
    __shared__ __align__(16) bf16 XS[64][72];            // 9.2 KB
    const int tid  = threadIdx.x;
    const int lane = tid & 63, wave = tid >> 6;
    const int i0   = blockIdx.x * 64;
    // stage W[256][128] f32 -> WT[128][256] bf16
    for (int idx = tid; idx < (F_INF * F_OUT) / 8; idx += 256) {
        int k  = idx >> 4;
        int n0 = (idx & 15) * 8;
        const float* src = W + (size_t)k * F_OUT + n0;
        float4 va = *(const float4*)(src);
        float4 vb = *(const float4*)(src + 4);
        float v[8] = {va.x, va.y, va.z, va.w, vb.x, vb.y, vb.z, vb.w};
#pragma unroll
        for (int c = 0; c < 8; ++c) WT[n0 + c][k] = f2b(v[c]);
    }
    __syncthreads();
    f32x4 acc[8];
#pragma unroll
    for (int t = 0; t < 8; ++t) acc[t] = {0.f, 0.f, 0.f, 0.f};
    const int m = lane & 15, quad = lane >> 4;
    const int rt = wave;
    for (int kc = 0; kc < F_INF / 64; ++kc) {
        const int k0 = kc * 64;
        {   // stage x chunk [64 rows][64 k] f32 -> bf16
            int part = tid & 7;
            int r    = tid >> 3;  // 0..31
#pragma unroll
            for (int p = 0; p < 2; ++p) {
                int rr = r + p * 32;
                const float* src = x + (size_t)(i0 + rr) * F_INF + k0 + part * 8;
                float4 va = *(const float4*)(src);
                float4 vb = *(const float4*)(src + 4);
                float v[8] = {va.x, va.y, va.z, va.w, vb.x, vb.y, vb.z, vb.w};
                __align__(16) bf16 th[8];
#pragma unroll
                for (int c = 0; c < 8; ++c) th[c] = f2b(v[c]);
                *(uint4*)(&XS[rr][part * 8]) = *(const uint4*)th;
            }
        }
        __syncthreads();
#pragma unroll
        for (int ks = 0; ks < 2; ++ks) {
            bf16x8 af = *(const bf16x8*)(&XS[rt * 16 + m][ks * 32 + quad * 8]);
#pragma unroll
            for (int ct = 0; ct < 8; ++ct) {
                bf16x8 bfr = *(const bf16x8*)(&WT[ct * 16 + m][k0 + ks * 32 + quad * 8]);
                acc[ct] = __builtin_amdgcn_mfma_f32_16x16x32_bf16(af, bfr, acc[ct], 0, 0, 0);
            }
        }
        __syncthreads();
    }
    // C/D: col=lane&15 -> f, row=quad*4+reg -> i
#pragma unroll
    for (int ct = 0; ct < 8; ++ct) {
        const int f = ct * 16 + m;
#pragma unroll
        for (int r = 0; r < 4; ++r) {
            const int i = i0 + rt * 16 + quad * 4 + r;
            hT[(size_t)f * N_NODES + i] = f2b(acc[ct][r]);
        }
    }
}

// ---------------- kernel 2: s1 = x@wa1, s2 = x@wa2 (exact fp32, wave per row) ----------------
__global__ __launch_bounds__(256) void k_s12(const float* __restrict__ x,
                                             const float* __restrict__ wa,
                                             float* __restrict__ s1,
                                             float* __restrict__ s2) {
    const int tid  = threadIdx.x;
    const int lane = tid & 63, wave = tid >> 6;
    float4 w1 = *(const float4*)(wa + lane * 4);
    float4 w2 = *(const float4*)(wa + F_INF + lane * 4);
    const int ibase = (blockIdx.x * 4 + wave) * 64;
    for (int r = 0; r < 64; ++r) {
        const int i = ibase + r;
        float4 xv = *(const float4*)(x + (size_t)i * F_INF + lane * 4);
        float v1 = xv.x * w1.x + xv.y * w1.y + xv.z * w1.z + xv.w * w1.w;
        float v2 = xv.x * w2.x + xv.y * w2.y + xv.z * w2.z + xv.w * w2.w;
#pragma unroll
        for (int off = 32; off >= 1; off >>= 1) {
            v1 += __shfl_xor(v1, off);
            v2 += __shfl_xor(v2, off);
        }
        if (lane == 0) { s1[i] = v1; s2[i] = v2; }
    }
}

// ---------------- kernel 3: global max of s2 ----------------
__global__ __launch_bounds__(256) void k_max(const float* __restrict__ s2,
                                             float* __restrict__ mg) {
    __shared__ float red[256];
    int tid = threadIdx.x;
    float m = -1e30f;
    for (int j = tid; j < N_NODES; j += 256) m = fmaxf(m, s2[j]);
    red[tid] = m;
    __syncthreads();
    for (int s = 128; s > 0; s >>= 1) {
        if (tid < s) red[tid] = fmaxf(red[tid], red[tid + s]);
        __syncthreads();
    }
    if (tid == 0) mg[0] = red[0];
}

// ---------------- kernel 4: flash attention, 64 rows x 1024-col j-octant ----------------
// 256 thr = 4 waves; wave = one 16-row tile, all 8 col-tiles, both k-halves.
// Lane (m,quad) computes P[wave*16+m][kh*32+quad*8..+7] directly in A-frag regs.
__global__ __launch_bounds__(256, 4) void k_attn(const int* __restrict__ adj,
                                                 const float* __restrict__ s1g,
                                                 const float* __restrict__ s2g,
                                                 const float* __restrict__ mg,
                                                 const bf16* __restrict__ hT,
                                                 float* __restrict__ Of,
                                                 float* __restrict__ lp) {
    __shared__ __align__(16) bf16 HS[F_OUT][72];   // h chunk [128 f][64 j], 18.4 KB
    __shared__ float s2s[1024];                    // 4 KB
    const int tid  = threadIdx.x;
    const int lane = tid & 63, wave = tid >> 6;
    const int m = lane & 15, quad = lane >> 4;
    const int i0    = blockIdx.x * 64;
    const int jq    = blockIdx.y;
    const int jbase = jq * 1024;
    const int irow  = i0 + wave * 16 + m;
    const float s1v = s1g[irow];
    const float tmi = s1v + mg[0];
    const float mi  = fmaxf(tmi, LRELU * tmi);  // >= every masked e of this row
    // stage s2 octant (1024 floats = 256 float4, one per thread)
    *(float4*)&s2s[tid * 4] = *(const float4*)(s2g + jbase + tid * 4);
    // HS staging: thread stages rows fr+{0,32,64,96}, cols part*8..+7
    const int part = tid & 7, fr = tid >> 3;
    const bf16* hTp = hT + jbase + part * 8;
    {
        uint4 v0 = *(const uint4*)(hTp + (size_t)(fr +  0) * N_NODES);
        uint4 v1 = *(const uint4*)(hTp + (size_t)(fr + 32) * N_NODES);
        uint4 v2 = *(const uint4*)(hTp + (size_t)(fr + 64) * N_NODES);
        uint4 v3 = *(const uint4*)(hTp + (size_t)(fr + 96) * N_NODES);
        *(uint4*)&HS[fr +  0][part * 8] = v0;
        *(uint4*)&HS[fr + 32][part * 8] = v1;
        *(uint4*)&HS[fr + 64][part * 8] = v2;
        *(uint4*)&HS[fr + 96][part * 8] = v3;
    }
    const int4* arowp = (const int4*)(adj + (size_t)irow * N_NODES + jbase);
    int4 av[4];  // prefetch chunk 0: kh0 ints [quad*8,+8), kh1 ints [32+quad*8,+8)
    av[0] = arowp[quad * 2];     av[1] = arowp[quad * 2 + 1];
    av[2] = arowp[8 + quad * 2]; av[3] = arowp[8 + quad * 2 + 1];
    float lacc = 0.f;
    f32x4 acc[8];
#pragma unroll
    for (int c = 0; c < 8; ++c) acc[c] = {0.f, 0.f, 0.f, 0.f};
    __syncthreads();   // HS(0) + s2s ready

    for (int jc = 0; jc < 16; ++jc) {
        const int jn = (jc < 15) ? jc + 1 : 15;
        // issue HS(jn) loads early; overlap with P-compute + MFMA
        uint4 h0 = *(const uint4*)(hTp + (size_t)(fr +  0) * N_NODES + jn * 64);
        uint4 h1 = *(const uint4*)(hTp + (size_t)(fr + 32) * N_NODES + jn * 64);
        uint4 h2 = *(const uint4*)(hTp + (size_t)(fr + 64) * N_NODES + jn * 64);
        uint4 h3 = *(const uint4*)(hTp + (size_t)(fr + 96) * N_NODES + jn * 64);
        // P-compute (both k-halves) from prefetched adj regs
        bf16x8 afrag[2];
#pragma unroll
        for (int kh = 0; kh < 2; ++kh) {
            const int am[8] = {av[kh*2].x, av[kh*2].y, av[kh*2].z, av[kh*2].w,
                               av[kh*2+1].x, av[kh*2+1].y, av[kh*2+1].z, av[kh*2+1].w};
            const float* s2p = &s2s[jc * 64 + kh * 32 + quad * 8];
            __align__(16) bf16 a8[8];
#pragma unroll
            for (int t = 0; t < 8; ++t) {
                float e = s1v + s2p[t];
                e = fmaxf(e, LRELU * e);
                float w = (am[t] > 0) ? __expf(e - mi) : 0.f;
                bf16 b = f2b(w);
                a8[t] = b;
                lacc += b2f(b);
            }
            afrag[kh] = *(const bf16x8*)a8;
        }
        // prefetch adj(jn)
        av[0] = arowp[jn * 16 + quad * 2];     av[1] = arowp[jn * 16 + quad * 2 + 1];
        av[2] = arowp[jn * 16 + 8 + quad * 2]; av[3] = arowp[jn * 16 + 8 + quad * 2 + 1];
        // O[16x128] += P[16x64] @ h[64x128]
#pragma unroll
        for (int kh = 0; kh < 2; ++kh)
#pragma unroll
            for (int c = 0; c < 8; ++c) {
                bf16x8 bfr = *(const bf16x8*)(&HS[c * 16 + m][kh * 32 + quad * 8]);
                acc[c] = __builtin_amdgcn_mfma_f32_16x16x32_bf16(afrag[kh], bfr, acc[c], 0, 0, 0);
            }
        __syncthreads();   // HS(jc) consumed
        *(uint4*)&HS[fr +  0][part * 8] = h0;
        *(uint4*)&HS[fr + 32][part * 8] = h1;
        *(uint4*)&HS[fr + 64][part * 8] = h2;
        *(uint4*)&HS[fr + 96][part * 8] = h3;
        __syncthreads();   // HS(jn) ready
    }
    // l: reduce over quads; each row owned by exactly one wave -> plain store
    lacc += __shfl_xor(lacc, 16);
    lacc += __shfl_xor(lacc, 32);
    if (quad == 0) lp[(size_t)jq * N_NODES + irow] = lacc;
    // Of: C/D col=m -> f, row=quad*4+r -> i
#pragma unroll
    for (int c = 0; c < 8; ++c) {
        const int f = c * 16 + m;
#pragma unroll
        for (int r = 0; r < 4; ++r) {
            const int i = i0 + wave * 16 + quad * 4 + r;
            Of[((size_t)jq * N_NODES + i) * F_OUT + f] = acc[c][r];
        }
    }
}

// ---------------- kernel 5: combine 8 partials, normalize, ELU, f32 out ----------------
__global__ __launch_bounds__(256) void k_comb(const float* __restrict__ Of,
                                              const float* __restrict__ lp,
                                              float* __restrict__ out) {
    size_t gid = (size_t)blockIdx.x * 256 + threadIdx.x;  // i*128+f
    int i = (int)(gid >> 7);
    float s = 0.f, l = 0.f;
#pragma unroll
    for (int q = 0; q < 8; ++q) {
        s += Of[(size_t)q * (N_NODES * (size_t)F_OUT) + gid];
        l += lp[q * N_NODES + i];
    }
    float o = s / l;
    out[gid] = o > 0.f ? o : __expf(o) - 1.f;
}

extern "C" void kernel_launch(void* const* d_in, const int* in_sizes, int n_in,
                              void* d_out, int out_size, void* d_ws, size_t ws_size,
                              hipStream_t stream) {
    (void)out_size; (void)ws_size;
    const float* x   = nullptr;
    const int*   adj = nullptr;
    const float* W   = nullptr;
    const float* a   = nullptr;
    for (int ii = 0; ii < n_in; ++ii) {
        int sz = in_sizes[ii];
        if      (sz == N_NODES * F_INF)  x   = (const float*)d_in[ii];
        else if (sz == F_INF * F_OUT)    W   = (const float*)d_in[ii];
        else if (sz == 2 * F_OUT)        a   = (const float*)d_in[ii];
        else                             adj = (const int*)d_in[ii];
    }
    float* out = (float*)d_out;

    char* ws = (char*)d_ws;
    bf16*  hT = (bf16*)ws;  ws += (size_t)F_OUT * N_NODES * 2;   // 2 MB
    float* wa = (float*)ws; ws += 2 * F_INF * 4;                 // 2 KB
    float* s1 = (float*)ws; ws += N_NODES * 4;
    float* s2 = (float*)ws; ws += N_NODES * 4;
    float* mg = (float*)ws; ws += 256;
    float* lp = (float*)ws; ws += 8 * N_NODES * 4;               // 256 KB
    float* Of = (float*)ws;                                      // 32 MB

    k_wa  <<<1, 256, 0, stream>>>(W, a, wa);
    k_xw  <<<N_NODES / 64, 256, 0, stream>>>(x, W, hT);
    k_s12 <<<N_NODES / 256, 256, 0, stream>>>(x, wa, s1, s2);
    k_max <<<1, 256, 0, stream>>>(s2, mg);
    k_attn<<<dim3(N_NODES / 64, 8), 256, 0, stream>>>(adj, s1, s2, mg, hT, Of, lp);
    k_comb<<<(N_NODES * F_OUT) / 256, 256, 0, stream>>>(Of, lp, out);
}

// Round 13
// 467.707 us; speedup vs baseline: 1.0307x; 1.0307x over previous
//
#include <hip/hip_runtime.h>
#include <hip/hip_bf16.h>
#include <stdint.h>

// GAT layer, MI355X. N=8192, F_in=256, F_out=128. All-f32 I/O.
// R13: (a) wa=W@a and s1/s2=x@wa fused into k_xw (no serial pre-kernels, no x re-read);
//      (b) k_attn double-buffered HS -> ONE barrier per chunk, adj prefetch depth 2.
// 4 kernels: k_xw -> k_max -> k_attn -> k_comb.

#define N_NODES 8192
#define F_INF   256
#define F_OUT   128
#define LRELU   0.01f

typedef __bf16 bf16x8 __attribute__((ext_vector_type(8)));
typedef float  f32x4  __attribute__((ext_vector_type(4)));
using bf16 = __hip_bfloat16;

__device__ __forceinline__ float b2f(bf16 v) { return __bfloat162float(v); }
__device__ __forceinline__ bf16  f2b(float v) { return __float2bfloat16(v); }

// ---------------- kernel 1: hT = bf16(x@W); fused wa = W@a, s1/s2 = x@wa (fp32) ----------------
// block: 64 rows, 256 threads = 4 waves; wave = one 16-row tile, all 8 col-tiles.
__global__ __launch_bounds__(256) void k_xw(const float* __restrict__ x,
                                            const float* __restrict__ W,
                                            const float* __restrict__ a,
                                            bf16* __restrict__ hT,
                                            float* __restrict__ s1,
                                            float* __restrict__ s2) {
    __shared__ __align__(16) bf16 WT[F_OUT][F_INF + 8];  // 67.6 KB
    __shared__ __align__(16) bf16 XS[64][72];            // 9.2 KB
    __shared__ float waL[2 * F_INF];                     // wa1[256] | wa2[256]
    __shared__ float s1L[64], s2L[64];
    const int tid  = threadIdx.x;
    const int lane = tid & 63, wave = tid >> 6;
    const int i0   = blockIdx.x * 64;
    waL[tid] = 0.f; waL[F_INF + tid] = 0.f;
    if (tid < 64) { s1L[tid] = 0.f; s2L[tid] = 0.f; }
    __syncthreads();
    // stage W[256][128] f32 -> WT[128][256] bf16, accumulate wa = W@a
    for (int idx = tid; idx < (F_INF * F_OUT) / 8; idx += 256) {
        int k  = idx >> 4;
        int n0 = (idx & 15) * 8;
        const float* src = W + (size_t)k * F_OUT + n0;
        float4 va = *(const float4*)(src);
        float4 vb = *(const float4*)(src + 4);
        float v[8] = {va.x, va.y, va.z, va.w, vb.x, vb.y, vb.z, vb.w};
        float p1 = 0.f, p2 = 0.f;
#pragma unroll
        for (int c = 0; c < 8; ++c) {
            WT[n0 + c][k] = f2b(v[c]);
            p1 += v[c] * a[n0 + c];
            p2 += v[c] * a[F_OUT + n0 + c];
        }
        atomicAdd(&waL[k], p1);
        atomicAdd(&waL[F_INF + k], p2);
    }
    __syncthreads();
    f32x4 acc[8];
#pragma unroll
    for (int t = 0; t < 8; ++t) acc[t] = {0.f, 0.f, 0.f, 0.f};
    const int m = lane & 15, quad = lane >> 4;
    const int rt = wave;
    for (int kc = 0; kc < F_INF / 64; ++kc) {
        const int k0 = kc * 64;
        {   // stage x chunk [64 rows][64 k]; accumulate s1/s2 partials (fp32 x * wa)
            int part = tid & 7;
            int r    = tid >> 3;  // 0..31
#pragma unroll
            for (int p = 0; p < 2; ++p) {
                int rr = r + p * 32;
                const float* src = x + (size_t)(i0 + rr) * F_INF + k0 + part * 8;
                float4 va = *(const float4*)(src);
                float4 vb = *(const float4*)(src + 4);
                float v[8] = {va.x, va.y, va.z, va.w, vb.x, vb.y, vb.z, vb.w};
                __align__(16) bf16 th[8];
                float q1 = 0.f, q2 = 0.f;
#pragma unroll
                for (int c = 0; c < 8; ++c) {
                    th[c] = f2b(v[c]);
                    q1 += v[c] * waL[k0 + part * 8 + c];
                    q2 += v[c] * waL[F_INF + k0 + part * 8 + c];
                }
                *(uint4*)(&XS[rr][part * 8]) = *(const uint4*)th;
                atomicAdd(&s1L[rr], q1);
                atomicAdd(&s2L[rr], q2);
            }
        }
        __syncthreads();
#pragma unroll
        for (int ks = 0; ks < 2; ++ks) {
            bf16x8 af = *(const bf16x8*)(&XS[rt * 16 + m][ks * 32 + quad * 8]);
#pragma unroll
            for (int ct = 0; ct < 8; ++ct) {
                bf16x8 bfr = *(const bf16x8*)(&WT[ct * 16 + m][kc * 64 + ks * 32 + quad * 8]);
                acc[ct] = __builtin_amdgcn_mfma_f32_16x16x32_bf16(af, bfr, acc[ct], 0, 0, 0);
            }
        }
        __syncthreads();
    }
    // C/D: col=lane&15 -> f, row=quad*4+reg -> i
#pragma unroll
    for (int ct = 0; ct < 8; ++ct) {
        const int f = ct * 16 + m;
#pragma unroll
        for (int r = 0; r < 4; ++r) {
            const int i = i0 + rt * 16 + quad * 4 + r;
            hT[(size_t)f * N_NODES + i] = f2b(acc[ct][r]);
        }
    }
    if (tid < 64) { s1[i0 + tid] = s1L[tid]; s2[i0 + tid] = s2L[tid]; }
}

// ---------------- kernel 2: global max of s2 ----------------
__global__ __launch_bounds__(256) void k_max(const float* __restrict__ s2,
                                             float* __restrict__ mg) {
    __shared__ float red[256];
    int tid = threadIdx.x;
    float m = -1e30f;
    for (int j = tid; j < N_NODES; j += 256) m = fmaxf(m, s2[j]);
    red[tid] = m;
    __syncthreads();
    for (int s = 128; s > 0; s >>= 1) {
        if (tid < s) red[tid] = fmaxf(red[tid], red[tid + s]);
        __syncthreads();
    }
    if (tid == 0) mg[0] = red[0];
}

// ---------------- kernel 3: flash attention, double-buffered HS, 1 barrier/chunk ----------------
// 64 rows x 1024-col j-octant, 256 thr = 4 waves; wave = 16-row tile, all 8 col-tiles.
// Lane (m,quad) computes P[wave*16+m][kh*32+quad*8..+7] directly in A-frag regs.
__global__ __launch_bounds__(256) void k_attn(const int* __restrict__ adj,
                                              const float* __restrict__ s1g,
                                              const float* __restrict__ s2g,
                                              const float* __restrict__ mg,
                                              const bf16* __restrict__ hT,
                                              float* __restrict__ Of,
                                              float* __restrict__ lp) {
    __shared__ __align__(16) bf16 HS[2][F_OUT][72];  // 36.9 KB double buffer
    __shared__ float s2s[1024];                      // 4 KB
    const int tid  = threadIdx.x;
    const int lane = tid & 63, wave = tid >> 6;
    const int m = lane & 15, quad = lane >> 4;
    const int i0    = blockIdx.x * 64;
    const int jq    = blockIdx.y;
    const int jbase = jq * 1024;
    const int irow  = i0 + wave * 16 + m;
    const float s1v = s1g[irow];
    const float tmi = s1v + mg[0];
    const float mi  = fmaxf(tmi, LRELU * tmi);  // >= every masked e of this row
    // stage s2 octant
    *(float4*)&s2s[tid * 4] = *(const float4*)(s2g + jbase + tid * 4);
    // HS staging: thread stages rows fr+{0,32,64,96}, cols part*8..+7
    const int part = tid & 7, fr = tid >> 3;
    const bf16* hTp = hT + jbase + part * 8;
    {   // chunk 0 -> HS[0]
        uint4 v0 = *(const uint4*)(hTp + (size_t)(fr +  0) * N_NODES);
        uint4 v1 = *(const uint4*)(hTp + (size_t)(fr + 32) * N_NODES);
        uint4 v2 = *(const uint4*)(hTp + (size_t)(fr + 64) * N_NODES);
        uint4 v3 = *(const uint4*)(hTp + (size_t)(fr + 96) * N_NODES);
        *(uint4*)&HS[0][fr +  0][part * 8] = v0;
        *(uint4*)&HS[0][fr + 32][part * 8] = v1;
        *(uint4*)&HS[0][fr + 64][part * 8] = v2;
        *(uint4*)&HS[0][fr + 96][part * 8] = v3;
    }
    // chunk 1 loads in flight (consumed next iteration's ds_write)
    uint4 h0 = *(const uint4*)(hTp + (size_t)(fr +  0) * N_NODES + 64);
    uint4 h1 = *(const uint4*)(hTp + (size_t)(fr + 32) * N_NODES + 64);
    uint4 h2 = *(const uint4*)(hTp + (size_t)(fr + 64) * N_NODES + 64);
    uint4 h3 = *(const uint4*)(hTp + (size_t)(fr + 96) * N_NODES + 64);
    // adj prefetch depth 2
    const int4* arowp = (const int4*)(adj + (size_t)irow * N_NODES + jbase);
    int4 avA[4], avB[4];
    avA[0] = arowp[quad * 2];          avA[1] = arowp[quad * 2 + 1];
    avA[2] = arowp[8 + quad * 2];      avA[3] = arowp[8 + quad * 2 + 1];
    avB[0] = arowp[16 + quad * 2];     avB[1] = arowp[16 + quad * 2 + 1];
    avB[2] = arowp[16 + 8 + quad * 2]; avB[3] = arowp[16 + 8 + quad * 2 + 1];
    float lacc = 0.f;
    f32x4 acc[8];
#pragma unroll
    for (int c = 0; c < 8; ++c) acc[c] = {0.f, 0.f, 0.f, 0.f};
    __syncthreads();   // HS[0] + s2s ready
    int b = 0;

    for (int jc = 0; jc < 16; ++jc) {
        // write next chunk (loaded a full chunk ago) into the other buffer
        if (jc < 15) {
            *(uint4*)&HS[b ^ 1][fr +  0][part * 8] = h0;
            *(uint4*)&HS[b ^ 1][fr + 32][part * 8] = h1;
            *(uint4*)&HS[b ^ 1][fr + 64][part * 8] = h2;
            *(uint4*)&HS[b ^ 1][fr + 96][part * 8] = h3;
        }
        // P-compute(jc) from prefetched adj regs (avA)
        bf16x8 afrag[2];
#pragma unroll
        for (int kh = 0; kh < 2; ++kh) {
            const int am[8] = {avA[kh*2].x, avA[kh*2].y, avA[kh*2].z, avA[kh*2].w,
                               avA[kh*2+1].x, avA[kh*2+1].y, avA[kh*2+1].z, avA[kh*2+1].w};
            const float* s2p = &s2s[jc * 64 + kh * 32 + quad * 8];
            __align__(16) bf16 a8[8];
#pragma unroll
            for (int t = 0; t < 8; ++t) {
                float e = s1v + s2p[t];
                e = fmaxf(e, LRELU * e);
                float w = (am[t] > 0) ? __expf(e - mi) : 0.f;
                bf16 bb = f2b(w);
                a8[t] = bb;
                lacc += b2f(bb);
            }
            afrag[kh] = *(const bf16x8*)a8;
        }
        // rotate adj prefetch: avA <- avB, avB <- chunk jc+2
#pragma unroll
        for (int q = 0; q < 4; ++q) avA[q] = avB[q];
        if (jc < 14) {
            const int base = (jc + 2) * 16;
            avB[0] = arowp[base + quad * 2];     avB[1] = arowp[base + quad * 2 + 1];
            avB[2] = arowp[base + 8 + quad * 2]; avB[3] = arowp[base + 8 + quad * 2 + 1];
        }
        // issue HS loads for chunk jc+2
        if (jc < 14) {
            const int off = (jc + 2) * 64;
            h0 = *(const uint4*)(hTp + (size_t)(fr +  0) * N_NODES + off);
            h1 = *(const uint4*)(hTp + (size_t)(fr + 32) * N_NODES + off);
            h2 = *(const uint4*)(hTp + (size_t)(fr + 64) * N_NODES + off);
            h3 = *(const uint4*)(hTp + (size_t)(fr + 96) * N_NODES + off);
        }
        // O[16x128] += P[16x64] @ h[64x128] from HS[b]
#pragma unroll
        for (int kh = 0; kh < 2; ++kh)
#pragma unroll
            for (int c = 0; c < 8; ++c) {
                bf16x8 bfr = *(const bf16x8*)(&HS[b][c * 16 + m][kh * 32 + quad * 8]);
                acc[c] = __builtin_amdgcn_mfma_f32_16x16x32_bf16(afrag[kh], bfr, acc[c], 0, 0, 0);
            }
        __syncthreads();   // readers of HS[b] done; HS[b^1] writes visible
        b ^= 1;
    }
    // l: reduce over quads; each row owned by exactly one (wave,m)
    lacc += __shfl_xor(lacc, 16);
    lacc += __shfl_xor(lacc, 32);
    if (quad == 0) lp[(size_t)jq * N_NODES + irow] = lacc;
    // Of: C/D col=m -> f, row=quad*4+r -> i
#pragma unroll
    for (int c = 0; c < 8; ++c) {
        const int f = c * 16 + m;
#pragma unroll
        for (int r = 0; r < 4; ++r) {
            const int i = i0 + wave * 16 + quad * 4 + r;
            Of[((size_t)jq * N_NODES + i) * F_OUT + f] = acc[c][r];
        }
    }
}

// ---------------- kernel 4: combine 8 partials, normalize, ELU, f32 out ----------------
__global__ __launch_bounds__(256) void k_comb(const float* __restrict__ Of,
                                              const float* __restrict__ lp,
                                              float* __restrict__ out) {
    size_t gid = (size_t)blockIdx.x * 256 + threadIdx.x;  // i*128+f
    int i = (int)(gid >> 7);
    float s = 0.f, l = 0.f;
#pragma unroll
    for (int q = 0; q < 8; ++q) {
        s += Of[(size_t)q * (N_NODES * (size_t)F_OUT) + gid];
        l += lp[q * N_NODES + i];
    }
    float o = s / l;
    out[gid] = o > 0.f ? o : __expf(o) - 1.f;
}

extern "C" void kernel_launch(void* const* d_in, const int* in_sizes, int n_in,
                              void* d_out, int out_size, void* d_ws, size_t ws_size,
                              hipStream_t stream) {
    (void)out_size; (void)ws_size;
    const float* x   = nullptr;
    const int*   adj = nullptr;
    const float* W   = nullptr;
    const float* a   = nullptr;
    for (int ii = 0; ii < n_in; ++ii) {
        int sz = in_sizes[ii];
        if      (sz == N_NODES * F_INF)  x   = (const float*)d_in[ii];
        else if (sz == F_INF * F_OUT)    W   = (const float*)d_in[ii];
        else if (sz == 2 * F_OUT)        a   = (const float*)d_in[ii];
        else                             adj = (const int*)d_in[ii];
    }
    float* out = (float*)d_out;

    char* ws = (char*)d_ws;
    bf16*  hT = (bf16*)ws;  ws += (size_t)F_OUT * N_NODES * 2;   // 2 MB
    float* s1 = (float*)ws; ws += N_NODES * 4;
    float* s2 = (float*)ws; ws += N_NODES * 4;
    float* mg = (float*)ws; ws += 256;
    float* lp = (float*)ws; ws += 8 * N_NODES * 4;               // 256 KB
    float* Of = (float*)ws;                                      // 32 MB

    k_xw  <<<N_NODES / 64, 256, 0, stream>>>(x, W, a, hT, s1, s2);
    k_max <<<1, 256, 0, stream>>>(s2, mg);
    k_attn<<<dim3(N_NODES / 64, 8), 256, 0, stream>>>(adj, s1, s2, mg, hT, Of, lp);
    k_comb<<<(N_NODES * F_OUT) / 256, 256, 0, stream>>>(Of, lp, out);
}